// Round 11
// baseline (441.171 us; speedup 1.0000x reference)
//
#include <hip/hip_runtime.h>
#include <hip/hip_bf16.h>

typedef unsigned short u16;
typedef short bf16x8 __attribute__((ext_vector_type(8)));
typedef float f32x4 __attribute__((ext_vector_type(4)));
typedef int   i32x4 __attribute__((ext_vector_type(4)));

#define NB 8
#define NT 1024
#define ND 512
#define KSEL 307
#define PSTR 152   // attn P LDS row stride (elems)
#define TSTR 136   // gemm_wh transpose LDS row stride (elems)
#define ASTR 520   // gemm2ln A LDS row stride (elems; 1040B -> 2-way bank alias, free)
#define NIT_G2L 4  // replication for counter visibility (idempotent)

__device__ __forceinline__ float bf2f(u16 u){
  union { unsigned int i; float f; } c; c.i = ((unsigned int)u) << 16; return c.f;
}
__device__ __forceinline__ u16 f2bf(float f){
  __hip_bfloat16 h = __float2bfloat16(f);
  u16 u; __builtin_memcpy(&u, &h, 2); return u;
}

// ---------- exact top-k selection by ranking; 4 threads per t, 64 t per block
__global__ void k_select(const float* __restrict__ mags, int* __restrict__ sel){
  __shared__ float sm[NT];
  int b = blockIdx.x;
  int tid = threadIdx.x;
  for (int i = tid; i < NT; i += 256) sm[i] = mags[b * NT + i];
  __syncthreads();
  int tl = tid >> 2, tq = tid & 3;
  int t = blockIdx.y * 64 + tl;
  float m = sm[t];
  int cnt = 0;
  int s0 = tq * 256;
  for (int s = s0; s < s0 + 256; s++){
    float v = sm[s];
    cnt += (v > m) || (v == m && s < t);
  }
  cnt += __shfl_xor(cnt, 1, 64);
  cnt += __shfl_xor(cnt, 2, 64);
  if (tq == 0) sel[b * NT + t] = (cnt < KSEL) ? 1 : 0;
}

// ---------- MFMA bf16 GEMM: Wh = bf16(x) @ W ; tile 128(t) x 64(f = one head)
//   Fused: cn zero (h==0), W2->bf16 W2T[n][k] transpose (h==2 pre-phase),
//          mags epilogue (h==0), es/ed edge dots, transposed bf16 WhT write.
//   (R4-verified, 143.7us baseline)
__launch_bounds__(256, 3)
__global__ void k_gemm_wh(const float* __restrict__ x, const float* __restrict__ Wf,
                          const float* __restrict__ W2f,
                          const float* __restrict__ a_src, const float* __restrict__ a_dst,
                          u16* __restrict__ WhT, float* __restrict__ es, float* __restrict__ ed,
                          float* __restrict__ mags, float* __restrict__ cn,
                          u16* __restrict__ W2T){
  __shared__ u16 smem[8704];
  u16* As = smem;
  u16* Bs = smem + 5120;
  int m0 = blockIdx.x * 128;
  int h  = blockIdx.y;
  int tid = threadIdx.x;
  if (h == 0 && tid < 64) cn[blockIdx.x * 64 + tid] = 0.f;
  if (h == 2){
    float* tile = (float*)smem;
    int kt0 = (blockIdx.x >> 3) * 64, n00 = (blockIdx.x & 7) * 64;
    int r = tid >> 6, cl = tid & 63;
#pragma unroll
    for (int p = 0; p < 16; p++)
      tile[(r + p*4)*65 + cl] = W2f[(size_t)(kt0 + r + p*4) * 512 + n00 + cl];
    __syncthreads();
#pragma unroll
    for (int p = 0; p < 16; p++){
      int orow = r + p*4;
      W2T[(size_t)(n00 + orow) * 512 + kt0 + cl] = f2bf(tile[cl*65 + orow]);
    }
    __syncthreads();
  }
  int wv = tid >> 6, lane = tid & 63;
  int quad = lane >> 4, lr = lane & 15;
  f32x4 acc[2][4] = {};
  float sq[2] = {0.f, 0.f};
  int ar = (tid * 8) >> 5, ac = (tid * 8) & 31;
  const float* xa0 = &x[(size_t)(m0 + ar) * 512 + ac];
  const float* xa1 = xa0 + (size_t)64 * 512;
  int kk = (tid * 8) >> 6, f0 = (tid * 8) & 63;
  const float* wb = &Wf[((size_t)h << 15) + (size_t)kk * 64 + f0];
  int bbase = f0 * 40 + (((kk >> 3) ^ ((f0 >> 3) & 3)) * 8) + (kk & 7);
  f32x4 pa0 = *(const f32x4*)xa0, pa1 = *(const f32x4*)(xa0 + 4);
  f32x4 pa2 = *(const f32x4*)xa1, pa3 = *(const f32x4*)(xa1 + 4);
  f32x4 pb0 = *(const f32x4*)wb,  pb1 = *(const f32x4*)(wb + 4);
  for (int kt = 0; kt < 512; kt += 32){
    __syncthreads();
    {
      u16 pk[8];
      if (h == 0){
#pragma unroll
        for (int q = 0; q < 4; q++) sq[0] += pa0[q]*pa0[q] + pa1[q]*pa1[q];
#pragma unroll
        for (int q = 0; q < 4; q++) sq[1] += pa2[q]*pa2[q] + pa3[q]*pa3[q];
      }
#pragma unroll
      for (int q = 0; q < 4; q++){ pk[q] = f2bf(pa0[q]); pk[4+q] = f2bf(pa1[q]); }
      *(bf16x8*)&As[ar*40 + ac] = *(const bf16x8*)pk;
#pragma unroll
      for (int q = 0; q < 4; q++){ pk[q] = f2bf(pa2[q]); pk[4+q] = f2bf(pa3[q]); }
      *(bf16x8*)&As[(ar + 64)*40 + ac] = *(const bf16x8*)pk;
#pragma unroll
      for (int q = 0; q < 4; q++) Bs[bbase + q*40]       = f2bf(pb0[q]);
#pragma unroll
      for (int q = 0; q < 4; q++) Bs[bbase + (q+4)*40]   = f2bf(pb1[q]);
    }
    __syncthreads();
    if (kt < 480){
      pa0 = *(const f32x4*)(xa0 + kt + 32); pa1 = *(const f32x4*)(xa0 + kt + 36);
      pa2 = *(const f32x4*)(xa1 + kt + 32); pa3 = *(const f32x4*)(xa1 + kt + 36);
      pb0 = *(const f32x4*)(wb + (size_t)(kt + 32) * 64);
      pb1 = *(const f32x4*)(wb + (size_t)(kt + 32) * 64 + 4);
    }
    bf16x8 af[2], bfr[4];
#pragma unroll
    for (int i = 0; i < 2; i++) af[i] = *(const bf16x8*)&As[(wv*32 + i*16 + lr)*40 + quad*8];
#pragma unroll
    for (int i = 0; i < 4; i++){
      int f = i*16 + lr;
      bfr[i] = *(const bf16x8*)&Bs[f*40 + ((quad ^ ((f >> 3) & 3)) * 8)];
    }
#pragma unroll
    for (int mi = 0; mi < 2; mi++)
#pragma unroll
      for (int ni = 0; ni < 4; ni++)
        acc[mi][ni] = __builtin_amdgcn_mfma_f32_16x16x32_bf16(af[mi], bfr[ni], acc[mi][ni], 0, 0, 0);
  }
  if (h == 0){
#pragma unroll
    for (int i = 0; i < 2; i++){
      float s = sq[i];
      s += __shfl_xor(s, 1, 64);
      s += __shfl_xor(s, 2, 64);
      if ((tid & 3) == 0) mags[m0 + i*64 + (tid >> 2)] = sqrtf(s);
    }
  }
  float asv[4], adv[4];
#pragma unroll
  for (int ni = 0; ni < 4; ni++){
    asv[ni] = a_src[h*64 + ni*16 + lr];
    adv[ni] = a_dst[h*64 + ni*16 + lr];
  }
#pragma unroll
  for (int mi = 0; mi < 2; mi++)
#pragma unroll
    for (int r = 0; r < 4; r++){
      float pes = 0.f, ped = 0.f;
#pragma unroll
      for (int ni = 0; ni < 4; ni++){
        pes += acc[mi][ni][r] * asv[ni];
        ped += acc[mi][ni][r] * adv[ni];
      }
#pragma unroll
      for (int mofs = 1; mofs < 16; mofs <<= 1){
        pes += __shfl_xor(pes, mofs, 64);
        ped += __shfl_xor(ped, mofs, 64);
      }
      if (lr == 0){
        int rowg = m0 + wv*32 + mi*16 + quad*4 + r;
        int bb_ = rowg >> 10, tt = rowg & 1023;
        es[(bb_ * 8 + h) * NT + tt] = pes;
        ed[(bb_ * 8 + h) * NT + tt] = ped;
      }
    }
  __syncthreads();
  u16* Tr = smem;
#pragma unroll
  for (int mi = 0; mi < 2; mi++)
#pragma unroll
    for (int ni = 0; ni < 4; ni++){
      int fl = ni*16 + lr;
      int tl = wv*32 + mi*16 + quad*4;
#pragma unroll
      for (int r = 0; r < 4; r++) Tr[fl*TSTR + tl + r] = f2bf(acc[mi][ni][r]);
    }
  __syncthreads();
  int f = tid >> 2, seg = tid & 3;
  int b_ = m0 >> 10;
  u16* dst = &WhT[(b_ * 512 + h * 64 + f) * NT + (m0 & 1023) + seg*32];
  const u16* srcp = &Tr[f*TSTR + seg*32];
#pragma unroll
  for (int k8 = 0; k8 < 4; k8++)
    *(bf16x8*)(dst + k8*8) = *(const bf16x8*)(srcp + k8*8);
}

// ---------- banded masked attention via MFMA + elu + signed-sqrt -> t2b (bf16)
//            + fused column sum-of-squares (atomicAdd into cn)
__launch_bounds__(256)
__global__ void k_attn(const u16* __restrict__ WhT, const float* __restrict__ es,
                       const float* __restrict__ ed, const int* __restrict__ sel,
                       u16* __restrict__ t2b, float* __restrict__ cn){
  __shared__ u16 P[64 * PSTR];
  __shared__ float edw[144];
  __shared__ int   selw[144];
  __shared__ float esw[64];
  __shared__ float swv[64];
  int bh = blockIdx.x;
  int b = bh >> 3;
  int t0 = blockIdx.y * 64;
  int tid = threadIdx.x;
  int wv = tid >> 6, lane = tid & 63;
  int quad = lane >> 4, lr = lane & 15;
  int s_base = t0 - 40;
  for (int i = tid; i < 144; i += 256){
    int s = s_base + i;
    bool ok = (s >= 0 && s < NT);
    edw[i]  = ok ? ed[bh * NT + s] : 0.f;
    selw[i] = ok ? sel[b * NT + s] : 0;
  }
  if (tid < 64) esw[tid] = es[bh * NT + t0 + tid];
  {
    i32x4 z = {};
    for (int i = lane; i < 304; i += 64){
      int r16 = i / 19, c16 = i - r16 * 19;
      *(i32x4*)&P[(16*wv + r16) * PSTR + c16 * 8] = z;
    }
  }
  __syncthreads();
  {
    int tl = 16*wv + (lane >> 2);
    int q = lane & 3;
    float e_t = esw[tl];
    int sel_t = selw[tl + 40];
    float part = 0.f;
    for (int j = q; j <= 80; j += 4){
      int sw = tl + j;
      int s = s_base + sw;
      float w = 0.f;
      if (s >= 0 && s < NT && (sel_t | selw[sw])){
        float v = e_t + edw[sw];
        v = v > 0.f ? v : 0.2f * v;
        v = fminf(v, 60.f);
        w = bf2f(f2bf(__expf(v)));
      }
      part += w;
      if (w != 0.f) P[tl * PSTR + sw] = f2bf(w);
    }
    part += __shfl_xor(part, 1, 64);
    part += __shfl_xor(part, 2, 64);
    if (q == 0) swv[tl] = part;
  }
  __syncthreads();
  f32x4 acc[4] = {};
  const u16* vbase = WhT + (bh * 64) * NT;
#pragma unroll
  for (int ks = 0; ks < 96; ks += 32){
    bf16x8 afr = *(const bf16x8*)&P[(16*wv + lr) * PSTR + 16*wv + ks + quad*8];
    int tb = s_base + 16*wv + ks + quad*8;
    bool ok = (tb >= 0) && (tb < NT);
    bf16x8 zf = {};
#pragma unroll
    for (int jn = 0; jn < 4; jn++){
      bf16x8 bfr = ok ? *(const bf16x8*)&vbase[(16*jn + lr) * NT + tb] : zf;
      acc[jn] = __builtin_amdgcn_mfma_f32_16x16x32_bf16(afr, bfr, acc[jn], 0, 0, 0);
    }
  }
#pragma unroll
  for (int jn = 0; jn < 4; jn++){
    float ssum = 0.f;
#pragma unroll
    for (int r = 0; r < 4; r++){
      int t_loc = 16*wv + quad*4 + r;
      float sw_ = swv[t_loc];
      float hp = acc[jn][r] / (sw_ > 0.f ? sw_ : 1.f);
      hp = hp > 0.f ? hp : (__expf(hp) - 1.f);
      float o = hp >= 0.f ? sqrtf(hp) : -sqrtf(-hp);
      ssum += o * o;
      t2b[(b * NT + t0 + t_loc) * ND + (bh & 7) * 64 + 16*jn + lr] = f2bf(o);
    }
    ssum += __shfl_xor(ssum, 16, 64);
    ssum += __shfl_xor(ssum, 32, 64);
    if (quad == 0) atomicAdd(&cn[b * ND + (bh & 7) * 64 + 16*jn + lr], ssum);
  }
}

// ---------- GEMM2+LN v3: 16(t) x 512(d), 512 thr, 512 blocks (2/CU).
//   A (pre-scaled bf16) staged in LDS ONCE -> K-loop has ZERO barriers.
//   B direct global->register, wave-private rows, 1-step register prefetch.
//   Disjoint LDS regions (54.7 KB): no alias hazards. NT stores for out.
//   REPLICATED x4 this round for counter visibility (idempotent).
__launch_bounds__(512, 4)
__global__ void k_gemm2ln(const u16* __restrict__ A, const u16* __restrict__ W2T,
                          const float* __restrict__ xres, const float* __restrict__ b2,
                          const float* __restrict__ cn, const float* __restrict__ g,
                          const float* __restrict__ bb, float* __restrict__ out){
  __shared__ __align__(16) char smraw[54656];
  u16*   As    = (u16*)smraw;             // 16 x ASTR(520) x 2B = 16640 B
  float* scl   = (float*)(smraw + 16640); // 2048 B
  float* wpart = (float*)(smraw + 18688); // 256 f32 = 1024 B
  float* mus   = (float*)(smraw + 19712); // 16 f32
  float* rss   = (float*)(smraw + 19776); // 16 f32 (end 19840)
  float* T     = (float*)(smraw + 19840); // [512 d][17] f32 = 34816 B (end 54656)
  int tid = threadIdx.x;
  int m0 = blockIdx.x * 16;
  int b  = m0 >> 10, t0 = m0 & 1023;
  int w = tid >> 6, lane = tid & 63;
  int quad = lane >> 4, lr = lane & 15;
  // per-thread pointers
  int arow = tid >> 5, acol = (tid & 31) * 16;           // A stage: 16 rows x 512
  const u16* ap = &A[(size_t)(m0 + arow) * 512 + acol];
  const u16* bp[4];
#pragma unroll
  for (int i = 0; i < 4; i++)
    bp[i] = &W2T[(size_t)(w*64 + i*16 + lr) * 512 + quad*8];

  for (int it = 0; it < NIT_G2L; ++it){
  __syncthreads();   // iter boundary (protects As/T reuse across iters)
  {
    float nv = sqrtf(cn[(b << 9) + tid]);
    scl[tid] = 1.f / fmaxf(nv, 1e-12f);
  }
  __syncthreads();
  // ---- stage pre-scaled A into LDS (once per iter)
  {
    bf16x8 r0 = *(const bf16x8*)ap;
    bf16x8 r1 = *(const bf16x8*)(ap + 8);
    u16 pk0[8], pk1[8];
#pragma unroll
    for (int q = 0; q < 8; q++){
      pk0[q] = f2bf(bf2f((u16)r0[q]) * scl[acol + q]);
      pk1[q] = f2bf(bf2f((u16)r1[q]) * scl[acol + 8 + q]);
    }
    *(bf16x8*)&As[arow*ASTR + acol]     = *(const bf16x8*)pk0;
    *(bf16x8*)&As[arow*ASTR + acol + 8] = *(const bf16x8*)pk1;
  }
  __syncthreads();   // A ready; K-loop below is barrier-free
  f32x4 acc[4] = {};
  bf16x8 cb0 = *(const bf16x8*)(bp[0]);
  bf16x8 cb1 = *(const bf16x8*)(bp[1]);
  bf16x8 cb2 = *(const bf16x8*)(bp[2]);
  bf16x8 cb3 = *(const bf16x8*)(bp[3]);
  for (int kt = 0; kt < 512; kt += 32){
    bf16x8 nb0, nb1, nb2, nb3;
    bool pf = kt < 480;
    if (pf){
      nb0 = *(const bf16x8*)(bp[0] + kt + 32);
      nb1 = *(const bf16x8*)(bp[1] + kt + 32);
      nb2 = *(const bf16x8*)(bp[2] + kt + 32);
      nb3 = *(const bf16x8*)(bp[3] + kt + 32);
    }
    bf16x8 af = *(const bf16x8*)&As[lr*ASTR + kt + quad*8];
    acc[0] = __builtin_amdgcn_mfma_f32_16x16x32_bf16(af, cb0, acc[0], 0, 0, 0);
    acc[1] = __builtin_amdgcn_mfma_f32_16x16x32_bf16(af, cb1, acc[1], 0, 0, 0);
    acc[2] = __builtin_amdgcn_mfma_f32_16x16x32_bf16(af, cb2, acc[2], 0, 0, 0);
    acc[3] = __builtin_amdgcn_mfma_f32_16x16x32_bf16(af, cb3, acc[3], 0, 0, 0);
    if (pf){ cb0 = nb0; cb1 = nb1; cb2 = nb2; cb3 = nb3; }
  }
  // ---- epilogue: yv = acc + xres + b2 ; block-local LN stats over 16 rows
  float b2v[4];
#pragma unroll
  for (int ni = 0; ni < 4; ni++) b2v[ni] = b2[w*64 + ni*16 + lr];
  float yv[4][4];
#pragma unroll
  for (int r = 0; r < 4; r++){
    int rl = quad*4 + r;
    float rs = 0.f, rq = 0.f;
#pragma unroll
    for (int ni = 0; ni < 4; ni++){
      int col = w*64 + ni*16 + lr;
      float v = acc[ni][r] + xres[(size_t)(m0 + rl) * 512 + col] + b2v[ni];
      yv[ni][r] = v;
      rs += v; rq += v * v;
    }
#pragma unroll
    for (int m2 = 1; m2 < 16; m2 <<= 1){
      rs += __shfl_xor(rs, m2, 64);
      rq += __shfl_xor(rq, m2, 64);
    }
    if (lr == 0){
      wpart[w*16 + rl]       = rs;
      wpart[128 + w*16 + rl] = rq;
    }
  }
  __syncthreads();
  if (tid < 16){
    float s = 0.f, q = 0.f;
#pragma unroll
    for (int wv2 = 0; wv2 < 8; wv2++){
      s += wpart[wv2*16 + tid];
      q += wpart[128 + wv2*16 + tid];
    }
    float mu = s * (1.f/512.f);
    float var = q * (1.f/512.f) - mu * mu;
    mus[tid] = mu;
    rss[tid] = 1.f / sqrtf(var + 1e-5f);
  }
  __syncthreads();
  float gv[4], bv[4];
#pragma unroll
  for (int ni = 0; ni < 4; ni++){
    gv[ni] = g[w*64 + ni*16 + lr];
    bv[ni] = bb[w*64 + ni*16 + lr];
  }
#pragma unroll
  for (int r = 0; r < 4; r++){
    int rl = quad*4 + r;
    float mu = mus[rl], rstd = rss[rl];
#pragma unroll
    for (int ni = 0; ni < 4; ni++){
      int col = w*64 + ni*16 + lr;
      T[col*17 + rl] = (yv[ni][r] - mu) * rstd * gv[ni] + bv[ni];
    }
  }
  __syncthreads();
  // write out[B,D,T]: 64 B contiguous per d, non-temporal
  int j = tid & 15, dq = tid >> 4;
#pragma unroll
  for (int kk2 = 0; kk2 < 16; kk2++){
    int d = dq + kk2 * 32;
    __builtin_nontemporal_store(T[d*17 + j],
        &out[((size_t)(b * 512 + d)) * 1024 + t0 + j]);
  }
  }
}

extern "C" void kernel_launch(void* const* d_in, const int* in_sizes, int n_in,
                              void* d_out, int out_size, void* d_ws, size_t ws_size,
                              hipStream_t stream) {
  (void)in_sizes; (void)n_in; (void)out_size; (void)ws_size;
  const float* x     = (const float*)d_in[0];
  const float* W     = (const float*)d_in[1];
  const float* a_src = (const float*)d_in[2];
  const float* a_dst = (const float*)d_in[3];
  const float* W2    = (const float*)d_in[4];
  const float* b2    = (const float*)d_in[5];
  const float* ln_g  = (const float*)d_in[6];
  const float* ln_b  = (const float*)d_in[7];
  char* ws = (char*)d_ws;
  int*   sel   = (int*)  (ws + 256);
  float* mags  = (float*)(ws + 33024);
  float* es    = (float*)(ws + 1124608);
  float* ed    = (float*)(ws + 1386752);
  float* cn    = (float*)(ws + 1648896);   // zeroed in k_gemm_wh h==0 blocks
  u16*   WhT   = (u16*)  (ws + 2097152);   // 8 MB; dead after k_attn
  u16*   t2b   = (u16*)  (ws + 18874368);  // 8 MB
  u16*   W2T   = (u16*)  (ws + 36175872);  // 512 KB bf16 W2[n][k] (k_gemm_wh h==2)
  float* out   = (float*)d_out;

  k_gemm_wh  <<<dim3(64, 8), 256, 0, stream>>>(x, W, W2, a_src, a_dst, WhT, es, ed, mags, cn, W2T);
  k_select   <<<dim3(NB, 16), 256, 0, stream>>>(mags, sel);
  k_attn     <<<dim3(64, 16), 256, 0, stream>>>(WhT, es, ed, sel, t2b, cn);
  k_gemm2ln  <<<dim3(512), 512, 0, stream>>>(t2b, W2T, x, b2, cn, ln_g, ln_b, out);
}

// Round 12
// 143.354 us; speedup vs baseline: 3.0775x; 3.0775x over previous
//
#include <hip/hip_runtime.h>
#include <hip/hip_bf16.h>

typedef unsigned short u16;
typedef short bf16x8 __attribute__((ext_vector_type(8)));
typedef float f32x4 __attribute__((ext_vector_type(4)));
typedef int   i32x4 __attribute__((ext_vector_type(4)));

#define NB 8
#define NT 1024
#define ND 512
#define KSEL 307
#define PSTR 152   // attn P LDS row stride (elems)
#define TSTR 136   // gemm_wh transpose LDS row stride (elems)

__device__ __forceinline__ float bf2f(u16 u){
  union { unsigned int i; float f; } c; c.i = ((unsigned int)u) << 16; return c.f;
}
__device__ __forceinline__ u16 f2bf(float f){
  __hip_bfloat16 h = __float2bfloat16(f);
  u16 u; __builtin_memcpy(&u, &h, 2); return u;
}

// ---------- exact top-k selection by ranking; 4 threads per t, 64 t per block
__global__ void k_select(const float* __restrict__ mags, int* __restrict__ sel){
  __shared__ float sm[NT];
  int b = blockIdx.x;
  int tid = threadIdx.x;
  for (int i = tid; i < NT; i += 256) sm[i] = mags[b * NT + i];
  __syncthreads();
  int tl = tid >> 2, tq = tid & 3;
  int t = blockIdx.y * 64 + tl;
  float m = sm[t];
  int cnt = 0;
  int s0 = tq * 256;
  for (int s = s0; s < s0 + 256; s++){
    float v = sm[s];
    cnt += (v > m) || (v == m && s < t);
  }
  cnt += __shfl_xor(cnt, 1, 64);
  cnt += __shfl_xor(cnt, 2, 64);
  if (tq == 0) sel[b * NT + t] = (cnt < KSEL) ? 1 : 0;
}

// ---------- MFMA bf16 GEMM: Wh = bf16(x) @ W ; tile 128(t) x 64(f = one head)
//   Fused: cn zero (h==0), W2->bf16 W2T[n][k] transpose (h==2 pre-phase),
//          mags epilogue (h==0), es/ed edge dots, transposed bf16 WhT write.
//   (R4-verified, 143.7us baseline)
__launch_bounds__(256, 3)
__global__ void k_gemm_wh(const float* __restrict__ x, const float* __restrict__ Wf,
                          const float* __restrict__ W2f,
                          const float* __restrict__ a_src, const float* __restrict__ a_dst,
                          u16* __restrict__ WhT, float* __restrict__ es, float* __restrict__ ed,
                          float* __restrict__ mags, float* __restrict__ cn,
                          u16* __restrict__ W2T){
  __shared__ u16 smem[8704];
  u16* As = smem;
  u16* Bs = smem + 5120;
  int m0 = blockIdx.x * 128;
  int h  = blockIdx.y;
  int tid = threadIdx.x;
  if (h == 0 && tid < 64) cn[blockIdx.x * 64 + tid] = 0.f;
  if (h == 2){
    float* tile = (float*)smem;
    int kt0 = (blockIdx.x >> 3) * 64, n00 = (blockIdx.x & 7) * 64;
    int r = tid >> 6, cl = tid & 63;
#pragma unroll
    for (int p = 0; p < 16; p++)
      tile[(r + p*4)*65 + cl] = W2f[(size_t)(kt0 + r + p*4) * 512 + n00 + cl];
    __syncthreads();
#pragma unroll
    for (int p = 0; p < 16; p++){
      int orow = r + p*4;
      W2T[(size_t)(n00 + orow) * 512 + kt0 + cl] = f2bf(tile[cl*65 + orow]);
    }
    __syncthreads();
  }
  int wv = tid >> 6, lane = tid & 63;
  int quad = lane >> 4, lr = lane & 15;
  f32x4 acc[2][4] = {};
  float sq[2] = {0.f, 0.f};
  int ar = (tid * 8) >> 5, ac = (tid * 8) & 31;
  const float* xa0 = &x[(size_t)(m0 + ar) * 512 + ac];
  const float* xa1 = xa0 + (size_t)64 * 512;
  int kk = (tid * 8) >> 6, f0 = (tid * 8) & 63;
  const float* wb = &Wf[((size_t)h << 15) + (size_t)kk * 64 + f0];
  int bbase = f0 * 40 + (((kk >> 3) ^ ((f0 >> 3) & 3)) * 8) + (kk & 7);
  f32x4 pa0 = *(const f32x4*)xa0, pa1 = *(const f32x4*)(xa0 + 4);
  f32x4 pa2 = *(const f32x4*)xa1, pa3 = *(const f32x4*)(xa1 + 4);
  f32x4 pb0 = *(const f32x4*)wb,  pb1 = *(const f32x4*)(wb + 4);
  for (int kt = 0; kt < 512; kt += 32){
    __syncthreads();
    {
      u16 pk[8];
      if (h == 0){
#pragma unroll
        for (int q = 0; q < 4; q++) sq[0] += pa0[q]*pa0[q] + pa1[q]*pa1[q];
#pragma unroll
        for (int q = 0; q < 4; q++) sq[1] += pa2[q]*pa2[q] + pa3[q]*pa3[q];
      }
#pragma unroll
      for (int q = 0; q < 4; q++){ pk[q] = f2bf(pa0[q]); pk[4+q] = f2bf(pa1[q]); }
      *(bf16x8*)&As[ar*40 + ac] = *(const bf16x8*)pk;
#pragma unroll
      for (int q = 0; q < 4; q++){ pk[q] = f2bf(pa2[q]); pk[4+q] = f2bf(pa3[q]); }
      *(bf16x8*)&As[(ar + 64)*40 + ac] = *(const bf16x8*)pk;
#pragma unroll
      for (int q = 0; q < 4; q++) Bs[bbase + q*40]       = f2bf(pb0[q]);
#pragma unroll
      for (int q = 0; q < 4; q++) Bs[bbase + (q+4)*40]   = f2bf(pb1[q]);
    }
    __syncthreads();
    if (kt < 480){
      pa0 = *(const f32x4*)(xa0 + kt + 32); pa1 = *(const f32x4*)(xa0 + kt + 36);
      pa2 = *(const f32x4*)(xa1 + kt + 32); pa3 = *(const f32x4*)(xa1 + kt + 36);
      pb0 = *(const f32x4*)(wb + (size_t)(kt + 32) * 64);
      pb1 = *(const f32x4*)(wb + (size_t)(kt + 32) * 64 + 4);
    }
    bf16x8 af[2], bfr[4];
#pragma unroll
    for (int i = 0; i < 2; i++) af[i] = *(const bf16x8*)&As[(wv*32 + i*16 + lr)*40 + quad*8];
#pragma unroll
    for (int i = 0; i < 4; i++){
      int f = i*16 + lr;
      bfr[i] = *(const bf16x8*)&Bs[f*40 + ((quad ^ ((f >> 3) & 3)) * 8)];
    }
#pragma unroll
    for (int mi = 0; mi < 2; mi++)
#pragma unroll
      for (int ni = 0; ni < 4; ni++)
        acc[mi][ni] = __builtin_amdgcn_mfma_f32_16x16x32_bf16(af[mi], bfr[ni], acc[mi][ni], 0, 0, 0);
  }
  if (h == 0){
#pragma unroll
    for (int i = 0; i < 2; i++){
      float s = sq[i];
      s += __shfl_xor(s, 1, 64);
      s += __shfl_xor(s, 2, 64);
      if ((tid & 3) == 0) mags[m0 + i*64 + (tid >> 2)] = sqrtf(s);
    }
  }
  float asv[4], adv[4];
#pragma unroll
  for (int ni = 0; ni < 4; ni++){
    asv[ni] = a_src[h*64 + ni*16 + lr];
    adv[ni] = a_dst[h*64 + ni*16 + lr];
  }
#pragma unroll
  for (int mi = 0; mi < 2; mi++)
#pragma unroll
    for (int r = 0; r < 4; r++){
      float pes = 0.f, ped = 0.f;
#pragma unroll
      for (int ni = 0; ni < 4; ni++){
        pes += acc[mi][ni][r] * asv[ni];
        ped += acc[mi][ni][r] * adv[ni];
      }
#pragma unroll
      for (int mofs = 1; mofs < 16; mofs <<= 1){
        pes += __shfl_xor(pes, mofs, 64);
        ped += __shfl_xor(ped, mofs, 64);
      }
      if (lr == 0){
        int rowg = m0 + wv*32 + mi*16 + quad*4 + r;
        int bb_ = rowg >> 10, tt = rowg & 1023;
        es[(bb_ * 8 + h) * NT + tt] = pes;
        ed[(bb_ * 8 + h) * NT + tt] = ped;
      }
    }
  __syncthreads();
  u16* Tr = smem;
#pragma unroll
  for (int mi = 0; mi < 2; mi++)
#pragma unroll
    for (int ni = 0; ni < 4; ni++){
      int fl = ni*16 + lr;
      int tl = wv*32 + mi*16 + quad*4;
#pragma unroll
      for (int r = 0; r < 4; r++) Tr[fl*TSTR + tl + r] = f2bf(acc[mi][ni][r]);
    }
  __syncthreads();
  int f = tid >> 2, seg = tid & 3;
  int b_ = m0 >> 10;
  u16* dst = &WhT[(b_ * 512 + h * 64 + f) * NT + (m0 & 1023) + seg*32];
  const u16* srcp = &Tr[f*TSTR + seg*32];
#pragma unroll
  for (int k8 = 0; k8 < 4; k8++)
    *(bf16x8*)(dst + k8*8) = *(const bf16x8*)(srcp + k8*8);
}

// ---------- banded masked attention via MFMA + elu + signed-sqrt -> t2b (bf16)
//            + fused column sum-of-squares (atomicAdd into cn)
__launch_bounds__(256)
__global__ void k_attn(const u16* __restrict__ WhT, const float* __restrict__ es,
                       const float* __restrict__ ed, const int* __restrict__ sel,
                       u16* __restrict__ t2b, float* __restrict__ cn){
  __shared__ u16 P[64 * PSTR];
  __shared__ float edw[144];
  __shared__ int   selw[144];
  __shared__ float esw[64];
  __shared__ float swv[64];
  int bh = blockIdx.x;
  int b = bh >> 3;
  int t0 = blockIdx.y * 64;
  int tid = threadIdx.x;
  int wv = tid >> 6, lane = tid & 63;
  int quad = lane >> 4, lr = lane & 15;
  int s_base = t0 - 40;
  for (int i = tid; i < 144; i += 256){
    int s = s_base + i;
    bool ok = (s >= 0 && s < NT);
    edw[i]  = ok ? ed[bh * NT + s] : 0.f;
    selw[i] = ok ? sel[b * NT + s] : 0;
  }
  if (tid < 64) esw[tid] = es[bh * NT + t0 + tid];
  {
    i32x4 z = {};
    for (int i = lane; i < 304; i += 64){
      int r16 = i / 19, c16 = i - r16 * 19;
      *(i32x4*)&P[(16*wv + r16) * PSTR + c16 * 8] = z;
    }
  }
  __syncthreads();
  {
    int tl = 16*wv + (lane >> 2);
    int q = lane & 3;
    float e_t = esw[tl];
    int sel_t = selw[tl + 40];
    float part = 0.f;
    for (int j = q; j <= 80; j += 4){
      int sw = tl + j;
      int s = s_base + sw;
      float w = 0.f;
      if (s >= 0 && s < NT && (sel_t | selw[sw])){
        float v = e_t + edw[sw];
        v = v > 0.f ? v : 0.2f * v;
        v = fminf(v, 60.f);
        w = bf2f(f2bf(__expf(v)));
      }
      part += w;
      if (w != 0.f) P[tl * PSTR + sw] = f2bf(w);
    }
    part += __shfl_xor(part, 1, 64);
    part += __shfl_xor(part, 2, 64);
    if (q == 0) swv[tl] = part;
  }
  __syncthreads();
  f32x4 acc[4] = {};
  const u16* vbase = WhT + (bh * 64) * NT;
#pragma unroll
  for (int ks = 0; ks < 96; ks += 32){
    bf16x8 afr = *(const bf16x8*)&P[(16*wv + lr) * PSTR + 16*wv + ks + quad*8];
    int tb = s_base + 16*wv + ks + quad*8;
    bool ok = (tb >= 0) && (tb < NT);
    bf16x8 zf = {};
#pragma unroll
    for (int jn = 0; jn < 4; jn++){
      bf16x8 bfr = ok ? *(const bf16x8*)&vbase[(16*jn + lr) * NT + tb] : zf;
      acc[jn] = __builtin_amdgcn_mfma_f32_16x16x32_bf16(afr, bfr, acc[jn], 0, 0, 0);
    }
  }
#pragma unroll
  for (int jn = 0; jn < 4; jn++){
    float ssum = 0.f;
#pragma unroll
    for (int r = 0; r < 4; r++){
      int t_loc = 16*wv + quad*4 + r;
      float sw_ = swv[t_loc];
      float hp = acc[jn][r] / (sw_ > 0.f ? sw_ : 1.f);
      hp = hp > 0.f ? hp : (__expf(hp) - 1.f);
      float o = hp >= 0.f ? sqrtf(hp) : -sqrtf(-hp);
      ssum += o * o;
      t2b[(b * NT + t0 + t_loc) * ND + (bh & 7) * 64 + 16*jn + lr] = f2bf(o);
    }
    ssum += __shfl_xor(ssum, 16, 64);
    ssum += __shfl_xor(ssum, 32, 64);
    if (quad == 0) atomicAdd(&cn[b * ND + (bh & 7) * 64 + 16*jn + lr], ssum);
  }
}

// ---------- GEMM2+LN fused v4: v1 structure (32t x 512d, 512 thr, 256 blocks)
//   + NON-TEMPORAL out stores (128B-granule in this layout -> no write
//     amplification; kills 32MB write-allocate fetch)
//   + NON-TEMPORAL t2b/xres loads (streamed-once data stops evicting W2T
//     from L2). Arithmetic bit-identical to the 143.7us R4 baseline.
__launch_bounds__(512)
__global__ void k_gemm2ln(const u16* __restrict__ A, const u16* __restrict__ W2T,
                          const float* __restrict__ xres, const float* __restrict__ b2,
                          const float* __restrict__ cn, const float* __restrict__ g,
                          const float* __restrict__ bb, float* __restrict__ out){
  __shared__ __align__(16) char smraw[69888];
  u16*   As  = (u16*)smraw;               // 32 x 40 = 2560 B
  u16*   Bs  = (u16*)(smraw + 2560);      // 512 x 40 = 40960 B (end 43520)
  float* scl = (float*)(smraw + 43520);   // 2048 B (end 45568)
  // post-K-loop aliases:
  float* T     = (float*)smraw;           // [512 d][33] f32 = 67584 B
  float* wpart = (float*)(smraw + 67584); // [2][8][32] = 2048 B
  float* mus   = (float*)(smraw + 69632); // 128 B
  float* rss   = (float*)(smraw + 69760); // 128 B
  int tid = threadIdx.x;
  int m0 = blockIdx.x * 32;               // global row base
  int b  = m0 >> 10, t0 = m0 & 1023;
  int w = tid >> 6, lane = tid & 63;
  int quad = lane >> 4, lr = lane & 15;
  // scl
  {
    float nv = sqrtf(cn[(b << 9) + tid]);
    scl[tid] = 1.f / fmaxf(nv, 1e-12f);
  }
  // staging prefetch (kt = 0)
  int ar = tid >> 2, ac = (tid & 3) * 8;        // A: threads 0..127
  const u16* ap = &A[(size_t)(m0 + ar) * 512 + ac];
  int nb_ = tid >> 2, c = (tid & 3) * 8;        // B: all threads, 4 reps
  bf16x8 ra = {}, rb[4];
  if (tid < 128) ra = __builtin_nontemporal_load((const bf16x8*)ap);
#pragma unroll
  for (int rep = 0; rep < 4; rep++)
    rb[rep] = *(const bf16x8*)&W2T[(size_t)(nb_ + rep*128) * 512 + c];
  f32x4 acc[2][4] = {};
  for (int kt = 0; kt < 512; kt += 32){
    __syncthreads();
    if (tid < 128){
      u16 pk[8];
#pragma unroll
      for (int q = 0; q < 8; q++)
        pk[q] = f2bf(bf2f((u16)ra[q]) * scl[kt + ac + q]);
      *(bf16x8*)&As[ar*40 + ac] = *(const bf16x8*)pk;
    }
#pragma unroll
    for (int rep = 0; rep < 4; rep++)
      *(bf16x8*)&Bs[(nb_ + rep*128)*40 + c] = rb[rep];
    __syncthreads();
    if (kt < 480){
      if (tid < 128) ra = __builtin_nontemporal_load((const bf16x8*)(ap + kt + 32));
#pragma unroll
      for (int rep = 0; rep < 4; rep++)
        rb[rep] = *(const bf16x8*)&W2T[(size_t)(nb_ + rep*128) * 512 + kt + 32 + c];
    }
    bf16x8 af[2], bfr[4];
#pragma unroll
    for (int mi = 0; mi < 2; mi++) af[mi] = *(const bf16x8*)&As[(mi*16 + lr)*40 + quad*8];
#pragma unroll
    for (int i = 0; i < 4; i++)
      bfr[i] = *(const bf16x8*)&Bs[(w*64 + i*16 + lr)*40 + quad*8];
#pragma unroll
    for (int mi = 0; mi < 2; mi++)
#pragma unroll
      for (int ni = 0; ni < 4; ni++)
        acc[mi][ni] = __builtin_amdgcn_mfma_f32_16x16x32_bf16(af[mi], bfr[ni], acc[mi][ni], 0, 0, 0);
  }
  // ---- epilogue: yv = acc + xres + b2 ; block-local LN stats
  float b2v[4];
#pragma unroll
  for (int ni = 0; ni < 4; ni++) b2v[ni] = b2[w*64 + ni*16 + lr];
  float yv[2][4][4];
#pragma unroll
  for (int mi = 0; mi < 2; mi++)
#pragma unroll
    for (int r = 0; r < 4; r++){
      int rl = mi*16 + quad*4 + r;
      float rs = 0.f, rq = 0.f;
#pragma unroll
      for (int ni = 0; ni < 4; ni++){
        int col = w*64 + ni*16 + lr;
        float v = acc[mi][ni][r]
                + __builtin_nontemporal_load(&xres[(size_t)(m0 + rl) * 512 + col])
                + b2v[ni];
        yv[mi][ni][r] = v;
        rs += v; rq += v * v;
      }
#pragma unroll
      for (int m2 = 1; m2 < 16; m2 <<= 1){
        rs += __shfl_xor(rs, m2, 64);
        rq += __shfl_xor(rq, m2, 64);
      }
      if (lr == 0){
        wpart[w*32 + rl]       = rs;
        wpart[256 + w*32 + rl] = rq;
      }
    }
  __syncthreads();     // wpart ready; all staging-LDS reads done
  if (tid < 32){
    float s = 0.f, q = 0.f;
#pragma unroll
    for (int wv2 = 0; wv2 < 8; wv2++){
      s += wpart[wv2*32 + tid];
      q += wpart[256 + wv2*32 + tid];
    }
    float mu = s * (1.f/512.f);
    float var = q * (1.f/512.f) - mu * mu;
    mus[tid] = mu;
    rss[tid] = 1.f / sqrtf(var + 1e-5f);
  }
  __syncthreads();
  // normalize into transpose tile T[d][t]
  float gv[4], bv[4];
#pragma unroll
  for (int ni = 0; ni < 4; ni++){
    gv[ni] = g[w*64 + ni*16 + lr];
    bv[ni] = bb[w*64 + ni*16 + lr];
  }
#pragma unroll
  for (int mi = 0; mi < 2; mi++)
#pragma unroll
    for (int r = 0; r < 4; r++){
      int rl = mi*16 + quad*4 + r;
      float mu = mus[rl], rstd = rss[rl];
#pragma unroll
      for (int ni = 0; ni < 4; ni++){
        int col = w*64 + ni*16 + lr;
        T[col*33 + rl] = (yv[mi][ni][r] - mu) * rstd * gv[ni] + bv[ni];
      }
    }
  __syncthreads();
  // write out[B,D,T]: 128 B contiguous per d, non-temporal (streamed, never re-read)
  int j = tid & 31, dq = tid >> 5;
#pragma unroll
  for (int kk2 = 0; kk2 < 32; kk2++){
    int d = dq + kk2 * 16;
    __builtin_nontemporal_store(T[d*33 + j],
        &out[((size_t)(b * 512 + d)) * 1024 + t0 + j]);
  }
}

extern "C" void kernel_launch(void* const* d_in, const int* in_sizes, int n_in,
                              void* d_out, int out_size, void* d_ws, size_t ws_size,
                              hipStream_t stream) {
  (void)in_sizes; (void)n_in; (void)out_size; (void)ws_size;
  const float* x     = (const float*)d_in[0];
  const float* W     = (const float*)d_in[1];
  const float* a_src = (const float*)d_in[2];
  const float* a_dst = (const float*)d_in[3];
  const float* W2    = (const float*)d_in[4];
  const float* b2    = (const float*)d_in[5];
  const float* ln_g  = (const float*)d_in[6];
  const float* ln_b  = (const float*)d_in[7];
  char* ws = (char*)d_ws;
  int*   sel   = (int*)  (ws + 256);
  float* mags  = (float*)(ws + 33024);
  float* es    = (float*)(ws + 1124608);
  float* ed    = (float*)(ws + 1386752);
  float* cn    = (float*)(ws + 1648896);   // zeroed in k_gemm_wh h==0 blocks
  u16*   WhT   = (u16*)  (ws + 2097152);   // 8 MB; dead after k_attn
  u16*   t2b   = (u16*)  (ws + 18874368);  // 8 MB
  u16*   W2T   = (u16*)  (ws + 36175872);  // 512 KB bf16 W2[n][k] (k_gemm_wh h==2)
  float* out   = (float*)d_out;

  k_gemm_wh  <<<dim3(64, 8), 256, 0, stream>>>(x, W, W2, a_src, a_dst, WhT, es, ed, mags, cn, W2T);
  k_select   <<<dim3(NB, 16), 256, 0, stream>>>(mags, sel);
  k_attn     <<<dim3(64, 16), 256, 0, stream>>>(WhT, es, ed, sel, t2b, cn);
  k_gemm2ln  <<<dim3(256), 512, 0, stream>>>(t2b, W2T, x, b2, cn, ln_g, ln_b, out);
}